// Round 1
// 501.407 us; speedup vs baseline: 1.0305x; 1.0305x over previous
//
#include <hip/hip_runtime.h>

typedef __attribute__((ext_vector_type(4))) float float4v;

#define TY    8            // rows per strip (block)
#define CXW   1024         // cols per chunk (block) = 256 threads * 4
#define CXP   (CXW + 8)    // LDS row width in floats (x-halo 4 each side)
#define NSLOT 8            // Ey' LDS ring depth (supports ns<=4)

__device__ __forceinline__ float4v ld4(const float* __restrict__ p) {
    return *(const float4v*)p;
}
__device__ __forceinline__ void st4(float* __restrict__ p, float4v v) {
    *(float4v*)p = v;
}
__device__ __forceinline__ float frcp(float x) {
    return __builtin_amdgcn_rcpf(x);
}

__device__ __forceinline__ void getC(int st, float C[4]) {
    C[0] = 1.f; C[1] = 0.f; C[2] = 0.f; C[3] = 0.f;
    if (st == 4)      { C[0] = 1.125f;          C[1] = -1.f / 24.f; }
    else if (st == 6) { C[0] = 75.f / 64.f;     C[1] = -25.f / 384.f;
                        C[2] = 3.f / 640.f; }
    else if (st == 8) { C[0] = 1225.f / 1024.f; C[1] = -245.f / 3072.f;
                        C[2] = 49.f / 5120.f;   C[3] = -5.f / 7168.f; }
}

// Fused E+H update. Each block: strip of TY rows x CXW cols for one batch b.
// Pipeline: compute Ey' row r = y0+e into LDS ring; once e >= ns, H-row
// h = r - ns has all its Ey' y-taps (h-ns+1 .. h+ns) resident in the ring.
__global__ __launch_bounds__(256) void fdtd_fused(
    const float* __restrict__ ca,   const float* __restrict__ cb,
    const float* __restrict__ cq,
    const float* __restrict__ Ey,   const float* __restrict__ Hx,
    const float* __restrict__ Hz,
    const float* __restrict__ mHxz, const float* __restrict__ mHzx,
    const float* __restrict__ mEyx, const float* __restrict__ mEyz,
    const float* __restrict__ ky,   const float* __restrict__ kyh,
    const float* __restrict__ ay,   const float* __restrict__ ayh,
    const float* __restrict__ by,   const float* __restrict__ byh,
    const float* __restrict__ kx,   const float* __restrict__ kxh,
    const float* __restrict__ ax,   const float* __restrict__ axh,
    const float* __restrict__ bx,   const float* __restrict__ bxh,
    const float* __restrict__ rdyp, const float* __restrict__ rdxp,
    const int* __restrict__ stp,
    float* __restrict__ outEy,   float* __restrict__ outHx,
    float* __restrict__ outHz,   float* __restrict__ outMHxz,
    float* __restrict__ outMHzx, float* __restrict__ outMEyx,
    float* __restrict__ outMEyz,
    int B, int NY, int NX, int NSTRIP, int NCHUNK)
{
    __shared__ float eyl[NSLOT][CXP];

    // XCD-chunked swizzle: y-adjacent strips land on the same XCD L2.
    const int nwg = NSTRIP * NCHUNK;
    int idx = blockIdx.x;
    if ((nwg & 7) == 0) {
        const int q = nwg >> 3;
        idx = (idx & 7) * q + (idx >> 3);
    }
    const int strip = idx % NSTRIP;
    const int chunk = idx / NSTRIP;
    const int b   = blockIdx.y;
    const int y0  = strip * TY;
    const int X0  = chunk * CXW;

    const int tid = (int)threadIdx.x;
    const int x0  = X0 + tid * 4;      // owned cols x0..x0+3
    const int lc0 = tid * 4;           // LDS col of (x0 - 4)

    const float rdx = rdxp[0];
    const float rdy = rdyp[0];
    int ns = stp[0] >> 1;
    if (ns < 1) ns = 1; if (ns > 4) ns = 4;
    float C[4]; getC(ns * 2, C);

    const size_t NXs = (size_t)NX;
    const size_t planeOff = (size_t)b * (size_t)NY * NXs;
    const float4v z4 = {0.f, 0.f, 0.f, 0.f};

    // per-thread x coefficients for the H update (col-invariant across rows)
    float4v kxhv = z4, axhv = z4, bxhv = z4, rkxh = z4;
    if (x0 + 4 <= NX) {
        kxhv = ld4(kxh + x0); axhv = ld4(axh + x0); bxhv = ld4(bxh + x0);
        #pragma unroll
        for (int i = 0; i < 4; ++i) rkxh[i] = frcp(kxhv[i]);
    }

    // ---- Ey' for 4 cols starting at xb (4-aligned) of row r ----
    auto computeE = [&](int r, int xb, bool wr,
                        float ayv, float byv, float rky) -> float4v {
        if (r < 0 || r >= NY || xb < 0 || xb >= NX) return z4;
        const size_t rb = planeOff + (size_t)r * NXs;
        // Hz x-window: w[j] = Hz[r][xb-4+j], j = 0..11 (zero-padded)
        float w[12];
        {
            float4v l0 = (xb >= 4)       ? ld4(Hz + rb + (xb - 4)) : z4;
            float4v l1 =                   ld4(Hz + rb + xb);
            float4v l2 = (xb + 8 <= NX)  ? ld4(Hz + rb + xb + 4)   : z4;
            w[0]=l0.x; w[1]=l0.y; w[2] =l0.z; w[3] =l0.w;
            w[4]=l1.x; w[5]=l1.y; w[6] =l1.z; w[7] =l1.w;
            w[8]=l2.x; w[9]=l2.y; w[10]=l2.z; w[11]=l2.w;
        }
        float dzx[4] = {0.f,0.f,0.f,0.f}, dxz[4] = {0.f,0.f,0.f,0.f};
        #pragma unroll
        for (int k = 1; k <= 4; ++k) {
            if (k <= ns) {
                const float ck = C[k - 1];
                #pragma unroll
                for (int i = 0; i < 4; ++i)        // taps x+k-1, x-k
                    dzx[i] += ck * (w[i + 3 + k] - w[i + 4 - k]);
                const int yp = r + k - 1, ym = r - k;
                float4v up = (yp < NY) ? ld4(Hx + rb + (size_t)(k - 1) * NXs + xb) : z4;
                float4v dn = (ym >= 0) ? ld4(Hx + rb - (size_t)k * NXs + xb)       : z4;
                #pragma unroll
                for (int i = 0; i < 4; ++i)
                    dxz[i] += ck * (up[i] - dn[i]);
            }
        }
        const size_t cr = (size_t)r * NXs + (size_t)xb;
        float4v eyv = ld4(Ey   + rb + xb);
        float4v mzx = ld4(mHzx + rb + xb);
        float4v mxz = ld4(mHxz + rb + xb);
        float4v cav = ld4(ca + cr);
        float4v cbv = ld4(cb + cr);
        float4v kxv = ld4(kx + xb);
        float4v axv = ld4(ax + xb);
        float4v bxv = ld4(bx + xb);
        float4v oE, oMxz, oMzx;
        #pragma unroll
        for (int i = 0; i < 4; ++i) {
            const float dHzdx = dzx[i] * rdx;
            const float dHxdz = dxz[i] * rdy;
            const float mzx_n = bxv[i] * mzx[i] + axv[i] * dHzdx;
            const float mxz_n = byv    * mxz[i] + ayv    * dHxdz;
            oE[i] = cav[i] * eyv[i]
                  + cbv[i] * ((dHzdx * frcp(kxv[i]) + mzx_n)
                            - (dHxdz * rky          + mxz_n));
            oMxz[i] = mxz_n;
            oMzx[i] = mzx_n;
        }
        if (wr) {
            st4(outEy   + rb + xb, oE);
            st4(outMHxz + rb + xb, oMxz);
            st4(outMHzx + rb + xb, oMzx);
        }
        return oE;
    };

    for (int e = 1 - ns; e < TY + ns; ++e) {
        const int r = y0 + e;
        float ayv = 0.f, byv = 0.f, rky = 0.f;
        if (r >= 0 && r < NY) {
            ayv = ay[r]; byv = by[r]; rky = frcp(ky[r]);
        }
        const bool wr = (e >= 0) && (e < TY);
        float4v eM = computeE(r, x0, wr, ayv, byv, rky);
        float4v eL = z4, eR = z4;
        if (tid == 0 && X0 >= 4)
            eL = computeE(r, X0 - 4, false, ayv, byv, rky);
        if (tid == 255 && X0 + CXW < NX)
            eR = computeE(r, X0 + CXW, false, ayv, byv, rky);

        __syncthreads();                       // prior H reads of this slot done
        const int slot = r & (NSLOT - 1);
        st4(&eyl[slot][lc0 + 4], eM);
        if (tid == 0)   st4(&eyl[slot][0],        eL);
        if (tid == 255) st4(&eyl[slot][CXW + 4],  eR);
        __syncthreads();                       // slot visible to whole block

        if (e >= ns) {
            const int h = r - ns;              // h in [y0, y0+TY)
            if (h < NY && x0 + 4 <= NX) {
                const size_t rb = planeOff + (size_t)h * NXs;
                const int hs = h & (NSLOT - 1);
                // Ey' x-window from own row: lw[j] = Ey'[h][x0-4+j], j=0..11
                float lw[12];
                {
                    float4v a0 = ld4(&eyl[hs][lc0]);
                    float4v a1 = ld4(&eyl[hs][lc0 + 4]);
                    float4v a2 = ld4(&eyl[hs][lc0 + 8]);
                    lw[0]=a0.x; lw[1]=a0.y; lw[2] =a0.z; lw[3] =a0.w;
                    lw[4]=a1.x; lw[5]=a1.y; lw[6] =a1.z; lw[7] =a1.w;
                    lw[8]=a2.x; lw[9]=a2.y; lw[10]=a2.z; lw[11]=a2.w;
                }
                float dEdx[4] = {0.f,0.f,0.f,0.f}, dEdz[4] = {0.f,0.f,0.f,0.f};
                #pragma unroll
                for (int k = 1; k <= 4; ++k) {
                    if (k <= ns) {
                        const float ck = C[k - 1];
                        #pragma unroll
                        for (int i = 0; i < 4; ++i)   // taps x+k, x-k+1
                            dEdx[i] += ck * (lw[i + 4 + k] - lw[i + 5 - k]);
                        float4v up = ld4(&eyl[(h + k)     & (NSLOT - 1)][lc0 + 4]);
                        float4v dn = ld4(&eyl[(h - k + 1) & (NSLOT - 1)][lc0 + 4]);
                        #pragma unroll
                        for (int i = 0; i < 4; ++i)
                            dEdz[i] += ck * (up[i] - dn[i]);
                    }
                }
                float4v hxv = ld4(Hx   + rb + x0);
                float4v hzv = ld4(Hz   + rb + x0);
                float4v mxv = ld4(mEyx + rb + x0);
                float4v mzv = ld4(mEyz + rb + x0);
                float4v cqv = ld4(cq + (size_t)h * NXs + x0);
                const float ayhv = ayh[h];
                const float byhv = byh[h];
                const float rkyh = frcp(kyh[h]);
                float4v oHx, oHz, oMx, oMz;
                #pragma unroll
                for (int i = 0; i < 4; ++i) {
                    const float dz = dEdz[i] * rdy;   // dEy_dz
                    const float dx = dEdx[i] * rdx;   // dEy_dx
                    const float mz_n = byhv    * mzv[i] + ayhv    * dz;
                    const float mx_n = bxhv[i] * mxv[i] + axhv[i] * dx;
                    oHx[i] = hxv[i] - cqv[i] * (dz * rkyh    + mz_n);
                    oHz[i] = hzv[i] + cqv[i] * (dx * rkxh[i] + mx_n);
                    oMx[i] = mx_n;
                    oMz[i] = mz_n;
                }
                st4(outHx   + rb + x0, oHx);
                st4(outHz   + rb + x0, oHz);
                st4(outMEyx + rb + x0, oMx);
                st4(outMEyz + rb + x0, oMz);
            }
        }
    }
}

extern "C" void kernel_launch(void* const* d_in, const int* in_sizes, int n_in,
                              void* d_out, int out_size, void* d_ws, size_t ws_size,
                              hipStream_t stream)
{
    const float* ca   = (const float*)d_in[0];
    const float* cb   = (const float*)d_in[1];
    const float* cq   = (const float*)d_in[2];
    const float* Ey   = (const float*)d_in[3];
    const float* Hx   = (const float*)d_in[4];
    const float* Hz   = (const float*)d_in[5];
    const float* mHxz = (const float*)d_in[6];
    const float* mHzx = (const float*)d_in[7];
    const float* mEyx = (const float*)d_in[8];
    const float* mEyz = (const float*)d_in[9];
    const float* ky   = (const float*)d_in[10];
    const float* kyh  = (const float*)d_in[11];
    const float* ay   = (const float*)d_in[12];
    const float* ayh  = (const float*)d_in[13];
    const float* by   = (const float*)d_in[14];
    const float* byh  = (const float*)d_in[15];
    const float* kx   = (const float*)d_in[16];
    const float* kxh  = (const float*)d_in[17];
    const float* ax   = (const float*)d_in[18];
    const float* axh  = (const float*)d_in[19];
    const float* bx   = (const float*)d_in[20];
    const float* bxh  = (const float*)d_in[21];
    const float* rdy  = (const float*)d_in[22];
    const float* rdx  = (const float*)d_in[23];
    const int*   stp  = (const int*)d_in[24];

    const int NX   = in_sizes[16];
    const int NYNX = in_sizes[0];
    const int NY   = NYNX / NX;
    const int B    = in_sizes[3] / NYNX;
    const size_t plane = (size_t)B * (size_t)NYNX;

    float* out     = (float*)d_out;
    float* outEy   = out;
    float* outHx   = out + 1 * plane;
    float* outHz   = out + 2 * plane;
    float* outMHxz = out + 3 * plane;
    float* outMHzx = out + 4 * plane;
    float* outMEyx = out + 5 * plane;
    float* outMEyz = out + 6 * plane;

    const int NSTRIP = (NY + TY - 1) / TY;
    const int NCHUNK = (NX + CXW - 1) / CXW;

    dim3 grid(NSTRIP * NCHUNK, B);
    dim3 block(256);

    fdtd_fused<<<grid, block, 0, stream>>>(
        ca, cb, cq, Ey, Hx, Hz, mHxz, mHzx, mEyx, mEyz,
        ky, kyh, ay, ayh, by, byh, kx, kxh, ax, axh, bx, bxh,
        rdy, rdx, stp,
        outEy, outHx, outHz, outMHxz, outMHzx, outMEyx, outMEyz,
        B, NY, NX, NSTRIP, NCHUNK);
}